// Round 12
// baseline (65.529 us; speedup 1.0000x reference)
//
#include <hip/hip_runtime.h>
#include <cstdint>

#define B_    2048
#define T_    2048
#define TD    7
#define NCHK  128        // chunks per row (= threads per block)
#define IDENT 0x4688u    // identity map: 0|1<<3|2<<6|3<<9|4<<12

// compose packed 5-slot maps: r[j] = f[g[j]]
__device__ __forceinline__ uint32_t mcompose(uint32_t f, uint32_t g) {
    uint32_t r = 0;
#pragma unroll
    for (int j = 0; j < 5; ++j) {
        uint32_t gj = (g >> (3 * j)) & 7u;
        r |= ((f >> (3 * gj)) & 7u) << (3 * j);
    }
    return r;
}

// pack two f32 -> bf16 pair (RNE), low half = first arg
__device__ __forceinline__ uint32_t cvtpk(float lo, float hi) {
    uint32_t r;
    asm("v_cvt_pk_bf16_f32 %0, %1, %2" : "=v"(r) : "v"(lo), "v"(hi));
    return r;
}

// extract bf16 halfword h from packed dword array (h compile-time after unroll)
__device__ __forceinline__ float xget(const uint32_t (&w)[40], int h) {
    return (h & 1) ? __uint_as_float(w[h >> 1] & 0xFFFF0000u)
                   : __uint_as_float(w[h >> 1] << 16);
}

// ---------------- compute core (register-resident x) ----------------

template<bool P>
__device__ __forceinline__ void hstep(const uint32_t (&w)[40], int base, bool pred,
                                      float (&dp)[5], const float (&tr)[5][5]) {
    float nd[5];
#pragma unroll
    for (int j = 0; j < 5; ++j) {
        float v = fmaxf(fmaxf(fmaxf(fmaxf(dp[0] + tr[0][j], dp[1] + tr[1][j]),
                                    dp[2] + tr[2][j]), dp[3] + tr[3][j]),
                        dp[4] + tr[4][j]);
        nd[j] = v + xget(w, base + j);
    }
#pragma unroll
    for (int j = 0; j < 5; ++j) dp[j] = (P && !pred) ? dp[j] : nd[j];
}

template<bool SEL>
__device__ __forceinline__ uint32_t lstep(const uint32_t (&w)[40], int base, bool mm,
                                          float (&dp)[5], const float (&tr)[5][5],
                                          uint32_t& rho) {
    float nd[5]; int aa[5]; uint32_t pk = 0;
#pragma unroll
    for (int j = 0; j < 5; ++j) {
        float s[5];
#pragma unroll
        for (int i = 0; i < 5; ++i) {
            float f = dp[i] + tr[i][j];
            uint32_t u = (__float_as_uint(f) & ~7u) | (uint32_t)(7 - i);  // v_and_or_b32
            s[i] = __uint_as_float(u);
        }
        float m = fmaxf(fmaxf(fmaxf(fmaxf(s[0], s[1]), s[2]), s[3]), s[4]); // 2x v_max3
        int a = 7 - (int)(__float_as_uint(m) & 7u);
        float v = m + xget(w, base + j);
        if (SEL) { a = mm ? a : j; nd[j] = mm ? v : dp[j]; }
        else     { nd[j] = v; }
        aa[j] = a;
        pk |= ((uint32_t)a) << (3 * j);
    }
    uint32_t nr = 0;
#pragma unroll
    for (int j = 0; j < 5; ++j) nr |= ((rho >> (3 * aa[j])) & 7u) << (3 * j);
    rho = nr;
#pragma unroll
    for (int j = 0; j < 5; ++j) dp[j] = nd[j];
    return pk;
}

// batch-load halo+live windows (20x ds_read_b128), then 15 halo + 16 live steps
template<bool AM>
__device__ __forceinline__ void fwd(const uint16_t* __restrict__ xs,
                                    const uint16_t* __restrict__ msk, int cc,
                                    const float (&tr)[5][5], const float (&ts)[5],
                                    float (&dp)[5], float (&dpE)[5],
                                    uint32_t (&acc)[8], uint32_t& rho) {
    const int hc = (cc > 0) ? cc - 1 : 0;
    const uint4* hp = (const uint4*)(xs + 88 * hc);   // 176B/chunk, 16B aligned
    const uint4* lp = (const uint4*)(xs + 88 * cc);
    uint32_t hw[40], lw[40];
#pragma unroll
    for (int q = 0; q < 10; ++q) {
        uint4 t = hp[q];
        hw[4*q] = t.x; hw[4*q+1] = t.y; hw[4*q+2] = t.z; hw[4*q+3] = t.w;
    }
#pragma unroll
    for (int q = 0; q < 10; ++q) {
        uint4 t = lp[q];
        lw[4*q] = t.x; lw[4*q+1] = t.y; lw[4*q+2] = t.z; lw[4*q+3] = t.w;
    }

#pragma unroll
    for (int j = 0; j < 5; ++j) dp[j] = xget(hw, j);
    if (cc <= 1) {
#pragma unroll
        for (int j = 0; j < 5; ++j) dp[j] += ts[j];
    }
    const uint32_t mh = AM ? 0xFFFFu : ((cc > 0) ? (uint32_t)msk[cc - 1] : 0u);
#pragma unroll
    for (int h = 1; h <= 15; ++h) {
        if (AM) hstep<false>(hw, 5 * h, true, dp, tr);
        else    hstep<true >(hw, 5 * h, ((mh >> h) & 1u) != 0, dp, tr);
    }
    if (AM && cc == 0) {      // AM halo ran on own data; restore exact t=0 init
#pragma unroll
        for (int j = 0; j < 5; ++j) dp[j] = xget(hw, j) + ts[j];
    }
#pragma unroll
    for (int j = 0; j < 5; ++j) dpE[j] = (cc == 0) ? 0.0f : dp[j];

    rho = IDENT;
    const uint32_t ml = AM ? 0xFFFFu : (uint32_t)msk[cc];
    acc[0] = lstep<true>(lw, 0, (cc != 0) && ((ml & 1u) != 0), dp, tr, rho);
#pragma unroll
    for (int l = 1; l < 16; ++l) {
        uint32_t pk;
        if (AM) pk = lstep<false>(lw, 5 * l, true, dp, tr, rho);
        else    pk = lstep<true >(lw, 5 * l, ((ml >> l) & 1u) != 0, dp, tr, rho);
        if (l & 1) acc[l >> 1] |= pk << 16;
        else       acc[l >> 1]  = pk;
    }
}

__global__ __launch_bounds__(128, 2) void k_all(
    const float* __restrict__ x, const int* __restrict__ mask,
    const float* __restrict__ tf, float* __restrict__ out)
{
    __shared__ __align__(16) uint16_t xs[11264];  // 128 chunks * 88 halfwords
    __shared__ uint16_t msk[NCHK];
    __shared__ uint32_t tot[2];
    __shared__ float    part[2];
    __shared__ int      lastS;

    const int b = blockIdx.x, c = threadIdx.x;
    const int lane = c & 63, w = c >> 6;

    const float4* gx = (const float4*)(x + (size_t)b * (T_ * 5));
    const int4*   gm = (const int4*)(mask + (size_t)b * T_);

    // ---- stage: coalesced loads -> bf16 pairs -> aligned LDS (ds_write_b64) ----
    float4 va[10], vb[10]; int4 m4[4];
#pragma unroll
    for (int q = 0; q < 10; ++q) va[q] = gx[c + 128 * q];
#pragma unroll
    for (int q = 0; q < 4; ++q) m4[q] = gm[4 * c + q];
#pragma unroll
    for (int q = 0; q < 10; ++q) vb[q] = gx[c + 128 * (10 + q)];

#pragma unroll
    for (int q = 0; q < 10; ++q) {
        int fi = c + 128 * q;
        int e0 = 4 * fi;
        int k  = (e0 * 52429) >> 22;          // e0/80 (exact in range)
        int h0 = e0 + 8 * k;                  // 88-halfword chunk stride
        uint2 p; p.x = cvtpk(va[q].x, va[q].y); p.y = cvtpk(va[q].z, va[q].w);
        *(uint2*)(xs + h0) = p;
    }
    uint32_t mb = 0;
#pragma unroll
    for (int q = 0; q < 4; ++q) {
        mb |= (m4[q].x ? 1u : 0u) << (4 * q);
        mb |= (m4[q].y ? 1u : 0u) << (4 * q + 1);
        mb |= (m4[q].z ? 1u : 0u) << (4 * q + 2);
        mb |= (m4[q].w ? 1u : 0u) << (4 * q + 3);
    }
    msk[c] = (uint16_t)mb;
#pragma unroll
    for (int q = 0; q < 10; ++q) {
        int fi = c + 128 * (10 + q);
        int e0 = 4 * fi;
        int k  = (e0 * 52429) >> 22;
        int h0 = e0 + 8 * k;
        uint2 p; p.x = cvtpk(vb[q].x, vb[q].y); p.y = cvtpk(vb[q].z, vb[q].w);
        *(uint2*)(xs + h0) = p;
    }

    float tr[5][5], ts[5], te[5];
#pragma unroll
    for (int i = 0; i < 5; ++i)
#pragma unroll
        for (int j = 0; j < 5; ++j) tr[i][j] = tf[i * TD + j];
#pragma unroll
    for (int j = 0; j < 5; ++j) ts[j] = tf[5 * TD + j];
#pragma unroll
    for (int j = 0; j < 5; ++j) te[j] = tf[j * TD + 6];

    const int allones = __syncthreads_and(mb == 0xFFFFu);

    float dp[5], dpE[5]; uint32_t acc[8], rho;
    if (allones) fwd<true >(xs, msk, c, tr, ts, dp, dpE, acc, rho);
    else         fwd<false>(xs, msk, c, tr, ts, dp, dpE, acc, rho);

    // exact per-chunk segment score of the decoded tree (within-lane telescoping)
    float svec[5];
#pragma unroll
    for (int j = 0; j < 5; ++j) {
        int r = (rho >> (3 * j)) & 7;
        float e = dpE[0];
        e = (r == 1) ? dpE[1] : e;
        e = (r == 2) ? dpE[2] : e;
        e = (r == 3) ? dpE[3] : e;
        e = (r == 4) ? dpE[4] : e;
        svec[j] = dp[j] - e;
    }

    // ---- intra-wave suffix composition (shfl, no barriers) ----
    uint32_t I = rho;
#pragma unroll
    for (int d = 1; d < 64; d <<= 1) {
        uint32_t oth = __shfl_down(I, d);
        uint32_t cm  = mcompose(I, oth);
        I = (lane + d < 64) ? cm : I;
    }
    if (lane == 0) tot[w] = I;
    if (c == NCHK - 1) {
        float best = dp[0] + te[0]; int last = 0;
#pragma unroll
        for (int j = 1; j < 5; ++j) {
            float s = dp[j] + te[j];
            if (s > best) { best = s; last = j; }
        }
        lastS = last;
    }
    __syncthreads();

    uint32_t Tw = (w == 0) ? tot[1] : IDENT;
    uint32_t Ex = __shfl_down(I, 1);
    uint32_t M  = (lane < 63) ? mcompose(Ex, Tw) : Tw;
    const int last = lastS;
    const int ec = (M >> (3 * last)) & 7;      // class at end of chunk c

    // ---- exact telescoped score: wave reduce + 2 partials ----
    {
        float v = svec[0];
        v = (ec == 1) ? svec[1] : v;
        v = (ec == 2) ? svec[2] : v;
        v = (ec == 3) ? svec[3] : v;
        v = (ec == 4) ? svec[4] : v;
        if (c == NCHK - 1) v += te[last];
#pragma unroll
        for (int off = 1; off < 64; off <<= 1) v += __shfl_xor(v, off);
        if (lane == 0) part[w] = v;
    }
    __syncthreads();
    if (c == 0) out[b] = part[0] + part[1];

    // ---- path decode from register bp ----
    float pv[16];
    int e = ec;
#pragma unroll
    for (int l = 15; l >= 0; --l) {
        pv[l] = (float)e;
        uint32_t p = (acc[l >> 1] >> (16 * (l & 1))) & 0xFFFFu;
        e = (p >> (3 * e)) & 7;
    }
    float* path = out + B_ + (size_t)b * T_ + c * 16;
#pragma unroll
    for (int q = 0; q < 4; ++q) {
        float4 v; v.x = pv[4*q]; v.y = pv[4*q+1]; v.z = pv[4*q+2]; v.w = pv[4*q+3];
        ((float4*)path)[q] = v;
    }
}

// ================= DIAGNOSTIC: staging phase only, x2 passes =================
// Identical addressing/instruction mix to k_all's stage. Junk output to ws.
__global__ __launch_bounds__(128, 2) void k_stage2(
    const float* __restrict__ x, const int* __restrict__ mask,
    float* __restrict__ ws)
{
    __shared__ __align__(16) uint16_t xs[11264];
    __shared__ uint16_t msk[NCHK];
    const int c = threadIdx.x;
    uint32_t keep = 0;

    for (int r = 0; r < 2; ++r) {
        const int b = (int)blockIdx.x ^ (r << 10);   // pass 0: row b; pass 1: row b^1024
        const float4* gx = (const float4*)(x + (size_t)b * (T_ * 5));
        const int4*   gm = (const int4*)(mask + (size_t)b * T_);

        float4 va[10], vb[10]; int4 m4[4];
#pragma unroll
        for (int q = 0; q < 10; ++q) va[q] = gx[c + 128 * q];
#pragma unroll
        for (int q = 0; q < 4; ++q) m4[q] = gm[4 * c + q];
#pragma unroll
        for (int q = 0; q < 10; ++q) vb[q] = gx[c + 128 * (10 + q)];

#pragma unroll
        for (int q = 0; q < 10; ++q) {
            int fi = c + 128 * q;
            int e0 = 4 * fi;
            int k  = (e0 * 52429) >> 22;
            int h0 = e0 + 8 * k;
            uint2 p; p.x = cvtpk(va[q].x, va[q].y); p.y = cvtpk(va[q].z, va[q].w);
            *(uint2*)(xs + h0) = p;
        }
        uint32_t mb = 0;
#pragma unroll
        for (int q = 0; q < 4; ++q) {
            mb |= (m4[q].x ? 1u : 0u) << (4 * q);
            mb |= (m4[q].y ? 1u : 0u) << (4 * q + 1);
            mb |= (m4[q].z ? 1u : 0u) << (4 * q + 2);
            mb |= (m4[q].w ? 1u : 0u) << (4 * q + 3);
        }
        msk[c] = (uint16_t)mb;
#pragma unroll
        for (int q = 0; q < 10; ++q) {
            int fi = c + 128 * (10 + q);
            int e0 = 4 * fi;
            int k  = (e0 * 52429) >> 22;
            int h0 = e0 + 8 * k;
            uint2 p; p.x = cvtpk(vb[q].x, vb[q].y); p.y = cvtpk(vb[q].z, vb[q].w);
            *(uint2*)(xs + h0) = p;
        }
        __syncthreads();
        // keep LDS live: dependent read (per-thread distinct addresses)
        keep += (uint32_t)xs[(c * 88) % 11264] + (uint32_t)msk[c];
        __syncthreads();
    }
    ws[(size_t)blockIdx.x * 128 + c] = (float)keep;
}

extern "C" void kernel_launch(void* const* d_in, const int* in_sizes, int n_in,
                              void* d_out, int out_size, void* d_ws, size_t ws_size,
                              hipStream_t stream) {
    const float* x         = (const float*)d_in[0];
    const int*   mask      = (const int*)d_in[1];
    const float* transform = (const float*)d_in[2];
    float*       out       = (float*)d_out;
    float*       ws        = (float*)d_ws;

    hipLaunchKernelGGL(k_all,    dim3(B_), dim3(128), 0, stream,
                       x, mask, transform, out);
    hipLaunchKernelGGL(k_stage2, dim3(B_), dim3(128), 0, stream,
                       x, mask, ws);
}

// Round 13
// 37.687 us; speedup vs baseline: 1.7388x; 1.7388x over previous
//
#include <hip/hip_runtime.h>
#include <cstdint>

#define B_    2048
#define T_    2048
#define TD    7
#define IDENT 0x4688u    // identity map: 0|1<<3|2<<6|3<<9|4<<12

// compose packed 5-slot maps: r[j] = f[g[j]]
__device__ __forceinline__ uint32_t mcompose(uint32_t f, uint32_t g) {
    uint32_t r = 0;
#pragma unroll
    for (int j = 0; j < 5; ++j) {
        uint32_t gj = (g >> (3 * j)) & 7u;
        r |= ((f >> (3 * gj)) & 7u) << (3 * j);
    }
    return r;
}

// pack two f32 -> bf16 pair (RNE), low half = first arg
__device__ __forceinline__ uint32_t cvtpk(float lo, float hi) {
    uint32_t r;
    asm("v_cvt_pk_bf16_f32 %0, %1, %2" : "=v"(r) : "v"(lo), "v"(hi));
    return r;
}

// extract bf16 halfword h from packed dword window (h compile-time after unroll)
__device__ __forceinline__ float xget(const uint32_t* w, int h) {
    return (h & 1) ? __uint_as_float(w[h >> 1] & 0xFFFF0000u)
                   : __uint_as_float(w[h >> 1] << 16);
}

// uint4 index of logical group q (0..19) of chunk cc, with per-chunk rotation
// slot=(q+(cc&7))%20 -> 8 consecutive lanes hit 8 distinct bank quads (free)
__device__ __forceinline__ int gidx(int cc, int q) {
    int s = q + (cc & 7);
    s = (s >= 20) ? s - 20 : s;
    return 20 * cc + s;
}

template<bool P>
__device__ __forceinline__ void hstep(const uint32_t* w, int base, bool pred,
                                      float (&dp)[5], const float (&tr)[5][5]) {
    float nd[5];
#pragma unroll
    for (int j = 0; j < 5; ++j) {
        float v = fmaxf(fmaxf(fmaxf(fmaxf(dp[0] + tr[0][j], dp[1] + tr[1][j]),
                                    dp[2] + tr[2][j]), dp[3] + tr[3][j]),
                        dp[4] + tr[4][j]);
        nd[j] = v + xget(w, base + j);
    }
#pragma unroll
    for (int j = 0; j < 5; ++j) dp[j] = (P && !pred) ? dp[j] : nd[j];
}

template<bool SEL>
__device__ __forceinline__ uint32_t lstep(const uint32_t* w, int base, bool mm,
                                          float (&dp)[5], const float (&tr)[5][5],
                                          uint32_t& rho) {
    float nd[5]; int aa[5]; uint32_t pk = 0;
#pragma unroll
    for (int j = 0; j < 5; ++j) {
        float s[5];
#pragma unroll
        for (int i = 0; i < 5; ++i) {
            float f = dp[i] + tr[i][j];
            uint32_t u = (__float_as_uint(f) & ~7u) | (uint32_t)(7 - i);  // v_and_or_b32
            s[i] = __uint_as_float(u);
        }
        float m = fmaxf(fmaxf(fmaxf(fmaxf(s[0], s[1]), s[2]), s[3]), s[4]); // 2x v_max3
        int a = 7 - (int)(__float_as_uint(m) & 7u);
        float v = m + xget(w, base + j);
        if (SEL) { a = mm ? a : j; nd[j] = mm ? v : dp[j]; }
        else     { nd[j] = v; }
        aa[j] = a;
        pk |= ((uint32_t)a) << (3 * j);
    }
    uint32_t nr = 0;
#pragma unroll
    for (int j = 0; j < 5; ++j) nr |= ((rho >> (3 * aa[j])) & 7u) << (3 * j);
    rho = nr;
#pragma unroll
    for (int j = 0; j < 5; ++j) dp[j] = nd[j];
    return pk;
}

__global__ __launch_bounds__(64) void k_all(
    const float* __restrict__ x, const int* __restrict__ mask,
    const float* __restrict__ tf, float* __restrict__ out)
{
    __shared__ __align__(16) uint16_t xs[10240];   // 20480 B EXACT -> 8 blocks/CU
    const int b = blockIdx.x, c = threadIdx.x;     // c = chunk (L=32), 64 chunks

    const float4* gx = (const float4*)(x + (size_t)b * (T_ * 5));
    const int*    gi = mask + (size_t)b * T_;

    // ---- stage x: 40 coalesced float4/thread -> bf16 pairs, rotated groups ----
#pragma unroll
    for (int qi = 0; qi < 40; ++qi) {
        int fi = c + 64 * qi;
        float4 v = gx[fi];
        uint32_t e0 = 4u * (uint32_t)fi;
        uint32_t co = e0 / 160u;                 // owning chunk
        uint32_t el = e0 - 160u * co;            // element within chunk
        uint32_t q  = el >> 3;                   // logical group
        uint32_t s  = q + (co & 7u); s = (s >= 20u) ? s - 20u : s;
        uint32_t ha = 160u * co + 8u * s + (el & 7u);
        uint2 p; p.x = cvtpk(v.x, v.y); p.y = cvtpk(v.z, v.w);
        *(uint2*)(xs + ha) = p;
    }

    // ---- mask: coalesced dword loads + ballot pack (32 bits per chunk) ----
    uint32_t mb = 0;
    {
        int mv[32];
#pragma unroll
        for (int q = 0; q < 32; ++q) mv[q] = gi[c + 64 * q];
#pragma unroll
        for (int q = 0; q < 32; ++q) {
            unsigned long long bal = __ballot(mv[q] != 0);
            if (c == 2 * q)     mb = (uint32_t)bal;
            if (c == 2 * q + 1) mb = (uint32_t)(bal >> 32);
        }
    }

    float tr[5][5], ts[5], te[5];
#pragma unroll
    for (int i = 0; i < 5; ++i)
#pragma unroll
        for (int j = 0; j < 5; ++j) tr[i][j] = tf[i * TD + j];
#pragma unroll
    for (int j = 0; j < 5; ++j) ts[j] = tf[5 * TD + j];
#pragma unroll
    for (int j = 0; j < 5; ++j) te[j] = tf[j * TD + 6];

    const bool allm = __all(mb == 0xFFFFFFFFu);
    uint32_t mh = __shfl_up(mb, 1);
    mh = (c > 0) ? (mh >> 16) : 0u;              // halo = prev chunk steps 16..31

    __syncthreads();                             // xs staged

    const uint4* xsv = (const uint4*)xs;
    const int hc = (c > 0) ? c - 1 : 0;

    // ---- halo: prev chunk groups 10..19 (steps 16..31), 15 warm-up steps ----
    uint32_t hwA[20], hwB[20];
#pragma unroll
    for (int k = 0; k < 5; ++k) {
        uint4 t = xsv[gidx(hc, 10 + k)];
        hwA[4*k] = t.x; hwA[4*k+1] = t.y; hwA[4*k+2] = t.z; hwA[4*k+3] = t.w;
    }
#pragma unroll
    for (int k = 0; k < 5; ++k) {
        uint4 t = xsv[gidx(hc, 15 + k)];
        hwB[4*k] = t.x; hwB[4*k+1] = t.y; hwB[4*k+2] = t.z; hwB[4*k+3] = t.w;
    }
    float dp[5];
#pragma unroll
    for (int j = 0; j < 5; ++j) dp[j] = xget(hwA, j);   // raw init at s0 (approx)
    if (allm) {
#pragma unroll
        for (int h = 1; h <= 7; ++h)  hstep<false>(hwA, 5 * h, true, dp, tr);
#pragma unroll
        for (int h = 8; h <= 15; ++h) hstep<false>(hwB, 5 * (h - 8), true, dp, tr);
    } else {
#pragma unroll
        for (int h = 1; h <= 7; ++h)  hstep<true>(hwA, 5 * h, ((mh >> h) & 1u) != 0, dp, tr);
#pragma unroll
        for (int h = 8; h <= 15; ++h) hstep<true>(hwB, 5 * (h - 8), ((mh >> h) & 1u) != 0, dp, tr);
    }
    if (c == 0) {                                // exact t=0 init (live l=0 masked)
        uint4 t0 = xsv[gidx(0, 0)];
        uint32_t w0[4] = { t0.x, t0.y, t0.z, t0.w };
#pragma unroll
        for (int j = 0; j < 5; ++j) dp[j] = xget(w0, j) + ts[j];
    }
    float dpE[5];
#pragma unroll
    for (int j = 0; j < 5; ++j) dpE[j] = (c == 0) ? 0.0f : dp[j];

    // ---- live: 32 exact steps, bp in registers, per-8-step group batches ----
    uint32_t acc[16];
    uint32_t rho = IDENT;
#pragma unroll
    for (int bb = 0; bb < 4; ++bb) {
        uint32_t w[20];
#pragma unroll
        for (int k = 0; k < 5; ++k) {
            uint4 t = xsv[gidx(c, 5 * bb + k)];
            w[4*k] = t.x; w[4*k+1] = t.y; w[4*k+2] = t.z; w[4*k+3] = t.w;
        }
#pragma unroll
        for (int ll = 0; ll < 8; ++ll) {
            const int l = 8 * bb + ll;
            uint32_t pk;
            if (l == 0) {
                bool mm = (c != 0) && ((mb & 1u) != 0);
                pk = lstep<true>(w, 0, mm, dp, tr, rho);
            } else if (allm) {
                pk = lstep<false>(w, 5 * ll, true, dp, tr, rho);
            } else {
                pk = lstep<true>(w, 5 * ll, ((mb >> l) & 1u) != 0, dp, tr, rho);
            }
            if (l & 1) acc[l >> 1] |= pk << 16;
            else       acc[l >> 1]  = pk;
        }
    }

    // exact per-chunk segment score of decoded tree (within-lane telescoping)
    float svec[5];
#pragma unroll
    for (int j = 0; j < 5; ++j) {
        int r = (rho >> (3 * j)) & 7;
        float e = dpE[0];
        e = (r == 1) ? dpE[1] : e;
        e = (r == 2) ? dpE[2] : e;
        e = (r == 3) ? dpE[3] : e;
        e = (r == 4) ? dpE[4] : e;
        svec[j] = dp[j] - e;
    }

    // ---- wave-local suffix composition over all 64 chunks ----
    uint32_t I = rho;
#pragma unroll
    for (int d = 1; d < 64; d <<= 1) {
        uint32_t oth = __shfl_down(I, d);
        uint32_t cm  = mcompose(I, oth);
        I = (c + d < 64) ? cm : I;
    }
    float best = dp[0] + te[0]; int lastv = 0;
#pragma unroll
    for (int j = 1; j < 5; ++j) {
        float s = dp[j] + te[j];
        if (s > best) { best = s; lastv = j; }
    }
    const int last = __shfl(lastv, 63);
    uint32_t M = __shfl_down(I, 1);
    M = (c < 63) ? M : IDENT;
    const int ec = (M >> (3 * last)) & 7;        // class at end of chunk c

    // ---- exact telescoped score: wave reduce ----
    {
        float v = svec[0];
        v = (ec == 1) ? svec[1] : v;
        v = (ec == 2) ? svec[2] : v;
        v = (ec == 3) ? svec[3] : v;
        v = (ec == 4) ? svec[4] : v;
        if (c == 63) v += te[last];
#pragma unroll
        for (int off = 1; off < 64; off <<= 1) v += __shfl_xor(v, off);
        if (c == 0) out[b] = v;
    }

    // ---- path decode from register bp ----
    float pv[32];
    int e = ec;
#pragma unroll
    for (int l = 31; l >= 0; --l) {
        pv[l] = (float)e;
        uint32_t p = (acc[l >> 1] >> (16 * (l & 1))) & 0xFFFFu;
        e = (p >> (3 * e)) & 7;
    }
    float* path = out + B_ + (size_t)b * T_ + c * 32;
#pragma unroll
    for (int q = 0; q < 8; ++q) {
        float4 v; v.x = pv[4*q]; v.y = pv[4*q+1]; v.z = pv[4*q+2]; v.w = pv[4*q+3];
        ((float4*)path)[q] = v;
    }
}

extern "C" void kernel_launch(void* const* d_in, const int* in_sizes, int n_in,
                              void* d_out, int out_size, void* d_ws, size_t ws_size,
                              hipStream_t stream) {
    const float* x         = (const float*)d_in[0];
    const int*   mask      = (const int*)d_in[1];
    const float* transform = (const float*)d_in[2];
    float*       out       = (float*)d_out;

    hipLaunchKernelGGL(k_all, dim3(B_), dim3(64), 0, stream,
                       x, mask, transform, out);
}